// Round 17
// baseline (1900.077 us; speedup 1.0000x reference)
//
#include <hip/hip_runtime.h>
#include <stdint.h>

#define T_SEQ 2048
#define HID 4096
#define NHEADS 32
#define I_FF 11008
#define QKV_N 12288
#define GU_N 22016

typedef unsigned short u16;
typedef unsigned int u32;
typedef __attribute__((ext_vector_type(4))) float f32x4;
typedef __attribute__((ext_vector_type(8))) __bf16 bf16x8;
typedef __attribute__((ext_vector_type(4))) u32 u32x4;
typedef __attribute__((ext_vector_type(2))) u32 u32x2;

__device__ __forceinline__ u16 f2bf(float f) {
  union { float f; u32 u; } v; v.f = f;
  u32 u = v.u;
  return (u16)((u + 0x7fffu + ((u >> 16) & 1u)) >> 16);
}
__device__ __forceinline__ float bf2f(u16 h) {
  union { u32 u; float f; } v; v.u = ((u32)h) << 16;
  return v.f;
}
__device__ __forceinline__ void split2(float x, u16& hi, u16& lo) {
  hi = f2bf(x);
  lo = f2bf(x - bf2f(hi));
}
// 8 floats -> hi-pack and lo-pack (each 8 bf16 in a u32x4)
__device__ __forceinline__ void split8(const float* v, u32x4& H, u32x4& L) {
#pragma unroll
  for (int j = 0; j < 4; j++) {
    u16 h0, l0, h1, l1;
    split2(v[2 * j], h0, l0);
    split2(v[2 * j + 1], h1, l1);
    H[j] = (u32)h0 | ((u32)h1 << 16);
    L[j] = (u32)l0 | ((u32)l1 << 16);
  }
}
// dequant 8 packed nibbles - zq -> bf16x8 fragment (exact values, cvt_pk rounds
// exactly). 8x(bfe,sub,cvt) + 4x v_cvt_pk_bf16_f32.
__device__ __forceinline__ bf16x8 dqfrag(u32 rbp, int zq) {
  u32x4 w;
#pragma unroll
  for (int j = 0; j < 4; j++) {
    int q0 = (int)((rbp >> (8 * j)) & 15u) - zq;
    int q1 = (int)((rbp >> (8 * j + 4)) & 15u) - zq;
    float f0 = (float)q0, f1 = (float)q1;
    u32 r;
    asm("v_cvt_pk_bf16_f32 %0, %1, %2" : "=v"(r) : "v"(f0), "v"(f1));
    w[j] = r;
  }
  return __builtin_bit_cast(bf16x8, w);
}

// ---------------- weight repack: int32 (0..15) -> packed nibbles ----------------
// pw[oct][n] u32, nibble j = qw[oct*8+j][n]
__global__ __launch_bounds__(256) void pack_qw_kernel(
    const int* __restrict__ qw, u32* __restrict__ pw, int N) {
  int n = blockIdx.x * 256 + threadIdx.x;
  int oct = blockIdx.y;
  const int* src = qw + (size_t)oct * 8 * N + n;
  u32 v = 0;
#pragma unroll
  for (int j = 0; j < 8; j++)
    v |= ((u32)src[(size_t)j * N] & 15u) << (4 * j);
  pw[(size_t)oct * N + n] = v;
}

// ---------------- RMSNorm: f32 in -> hi bf16 plane ----------------
__global__ __launch_bounds__(256) void rmsnorm_kernel(
    const float* __restrict__ in, const float* __restrict__ w,
    u16* __restrict__ outh) {
  int row = blockIdx.x;
  const float* x = in + (size_t)row * HID;
  float4 vals[4];
  float ss = 0.f;
#pragma unroll
  for (int k = 0; k < 4; k++) {
    vals[k] = ((const float4*)x)[threadIdx.x + k * 256];
    ss += vals[k].x * vals[k].x + vals[k].y * vals[k].y +
          vals[k].z * vals[k].z + vals[k].w * vals[k].w;
  }
#pragma unroll
  for (int o = 1; o < 64; o <<= 1) ss += __shfl_xor(ss, o);
  __shared__ float red[4];
  if ((threadIdx.x & 63) == 0) red[threadIdx.x >> 6] = ss;
  __syncthreads();
  ss = red[0] + red[1] + red[2] + red[3];
  float rs = rsqrtf(ss * (1.f / HID) + 1e-6f);
#pragma unroll
  for (int k = 0; k < 4; k++) {
    int c4 = threadIdx.x + k * 256;
    float4 wv = ((const float4*)w)[c4];
    float o[4] = {vals[k].x * rs * wv.x, vals[k].y * rs * wv.y,
                  vals[k].z * rs * wv.z, vals[k].w * rs * wv.w};
    u32x2 H;
    H[0] = (u32)f2bf(o[0]) | ((u32)f2bf(o[1]) << 16);
    H[1] = (u32)f2bf(o[2]) | ((u32)f2bf(o[3]) << 16);
    *(u32x2*)(outh + (size_t)row * HID + c4 * 4) = H;
  }
}

// ---------------- AWQ GEMM, BN=256, A-hi via LDS, B direct global->reg ----------------
// BM=128 BN=256 BK=32, 8 waves (2M x 4N), per-wave 64x64 out (4m x 4n frags).
// B fragment = one packed u32 per lane per frag, loaded from L2-hot pw,
// dequanted in-register (exact (q-z)->bf16). LDS holds only A (20KB).
// Telescoping per-group scale rescale. m-partitioned XCD decode.
template <bool RESID, bool OUTBF16>
__global__ __launch_bounds__(512) void awq_gemm256r_kernel(
    const u16* __restrict__ Ahg,
    const u32* __restrict__ pw, const float* __restrict__ scales,
    const int* __restrict__ qz, const float* __restrict__ resid,
    void* __restrict__ outp, int N, int K, int nstrips) {
  __shared__ u16 AhL[2][128][40];
  int tid = threadIdx.x;
  int lane = tid & 63;
  int wid = tid >> 6;
  int g16 = lane >> 4, l16 = lane & 15;
  int p = blockIdx.x;
  int xcd = p & 7;
  int idx = p >> 3;
  int s = idx >> 1;
  int mi = ((idx & 1) << 3) + xcd;
  if (s >= nstrips) return;
  int m0 = mi * 128;
  int n0 = s * 256;
  int wr = wid >> 2, wc = wid & 3;   // 2 row halves x 4 col quarters

  f32x4 acc[4][4] = {};
  float svold[4];
  int zqv[4];

  // A staging: thread -> (row, 8-wide k-chunk), one 16B load per thread
  int a_row = tid >> 2, a_kc = (tid & 3) * 8;
  const u16* aph = Ahg + (size_t)(m0 + a_row) * K + a_kc;
  // per-lane B/zq/scale column base: col(n) = colb + n*16
  int colb = n0 + wc * 64 + l16;
  const u32* pwl = pw + (size_t)g16 * N + colb;   // + (4ks)*N + n*16
  const int* qzl = qz + colb;                     // + g*N + n*16
  const float* scl = scales + n0;                 // lane-indexed below

  int nsteps = K >> 5;

  u32x4 rah, rahn;
  u32 rbv[4], rbn[4];

  // prologue: step 0
  rah = *(const u32x4*)(aph);
#pragma unroll
  for (int n = 0; n < 4; n++) rbv[n] = pwl[n * 16];
  *(u32x4*)&AhL[0][a_row][a_kc] = rah;
#pragma unroll
  for (int n = 0; n < 4; n++) {
    zqv[n] = qzl[n * 16];
    svold[n] = scl[wc * 64 + n * 16 + l16];
  }
  __syncthreads();

  int cur = 0;
  for (int ks = 0; ks < nsteps; ks++) {
    int nxt = ks + 1;
    if (nxt < nsteps) {
      rahn = *(const u32x4*)(aph + (nxt << 5));
      const u32* q = pwl + (size_t)(nxt << 2) * N;
#pragma unroll
      for (int n = 0; n < 4; n++) rbn[n] = q[n * 16];
    }
    // entering a new scale group: reload zq, rescale acc into new scale units
    if (ks != 0 && (ks & 3) == 0) {
      int g = ks >> 2;
#pragma unroll
      for (int n = 0; n < 4; n++) {
        zqv[n] = qzl[(size_t)g * N + n * 16];
        float svnew = scl[(size_t)g * N + wc * 64 + n * 16 + l16];
        float r = svold[n] * __builtin_amdgcn_rcpf(svnew);
        svold[n] = svnew;
#pragma unroll
        for (int m = 0; m < 4; m++)
#pragma unroll
          for (int i = 0; i < 4; i++) acc[m][n][i] *= r;
      }
    }
    // dequant this step's B fragments in-register
    bf16x8 bq[4];
#pragma unroll
    for (int n = 0; n < 4; n++) bq[n] = dqfrag(rbv[n], zqv[n]);
    // A fragments from LDS, MFMA
#pragma unroll
    for (int m = 0; m < 4; m++) {
      bf16x8 ah = __builtin_bit_cast(bf16x8,
          *(const u32x4*)&AhL[cur][wr * 64 + m * 16 + l16][g16 * 8]);
#pragma unroll
      for (int n = 0; n < 4; n++)
        acc[m][n] = __builtin_amdgcn_mfma_f32_16x16x32_bf16(ah, bq[n], acc[m][n], 0, 0, 0);
    }
    if (nxt < nsteps) {
      *(u32x4*)&AhL[cur ^ 1][a_row][a_kc] = rahn;   // write-late (other buffer)
#pragma unroll
      for (int n = 0; n < 4; n++) rbv[n] = rbn[n];
    }
    __syncthreads();
    cur ^= 1;
  }
  // fold final group scale
#pragma unroll
  for (int n = 0; n < 4; n++)
#pragma unroll
    for (int m = 0; m < 4; m++)
#pragma unroll
      for (int i = 0; i < 4; i++) acc[m][n][i] *= svold[n];
  // epilogue: C layout col=lane&15, row=(lane>>4)*4+reg
#pragma unroll
  for (int m = 0; m < 4; m++) {
#pragma unroll
    for (int n = 0; n < 4; n++) {
#pragma unroll
      for (int r = 0; r < 4; r++) {
        int row = m0 + wr * 64 + m * 16 + g16 * 4 + r;
        int col = n0 + wc * 64 + n * 16 + l16;
        float v = acc[m][n][r];
        if (RESID) v += resid[(size_t)row * N + col];
        if (OUTBF16)
          ((u16*)outp)[(size_t)row * N + col] = f2bf(v);
        else
          ((float*)outp)[(size_t)row * N + col] = v;
      }
    }
  }
}

// ---------------- RoPE in-place on q,k of qkv (f32) ----------------
__global__ __launch_bounds__(256) void rope_kernel(float* __restrict__ qkv) {
  int t = blockIdx.x;
  __shared__ float cs[64], sn[64];
  if (threadIdx.x < 64) {
    int i = threadIdx.x;
    float freq = exp2f(-(float)i * (13.287712379549449f / 64.f));
    float ang = (float)t * freq;
    cs[i] = cosf(ang);
    sn[i] = sinf(ang);
  }
  __syncthreads();
#pragma unroll
  for (int it = 0; it < 16; it++) {
    int idx = threadIdx.x + it * 256;
    int part = idx >> 11;
    int rem = idx & 2047;
    int hh = rem >> 6, i = rem & 63;
    float* base = qkv + (size_t)t * QKV_N + (size_t)part * HID + hh * 128;
    float x1 = base[i], x2 = base[64 + i];
    float c = cs[i], s = sn[i];
    base[i] = x1 * c - x2 * s;
    base[64 + i] = x2 * c + x1 * s;
  }
}

// ---------------- transpose V section of qkv(f32) -> vt[H][T] bf16 ----------------
__global__ __launch_bounds__(256) void transpose_v_kernel(
    const float* __restrict__ qkv, u16* __restrict__ vt) {
  __shared__ u16 tile[64][65];
  int tb = blockIdx.x;
  int cb = blockIdx.y;
  int tid = threadIdx.x;
  int r = tid >> 2, c16 = (tid & 3) * 16;
  const float* src = qkv + (size_t)(tb * 64 + r) * QKV_N + 2 * HID + cb * 64 + c16;
  float v[16];
  *(float4*)&v[0] = *(const float4*)(src);
  *(float4*)&v[4] = *(const float4*)(src + 4);
  *(float4*)&v[8] = *(const float4*)(src + 8);
  *(float4*)&v[12] = *(const float4*)(src + 12);
#pragma unroll
  for (int i = 0; i < 16; i++) tile[r][c16 + i] = f2bf(v[i]);
  __syncthreads();
  int ocol = tid >> 2, tchunk = (tid & 3) * 16;
  u16 vbuf[16];
#pragma unroll
  for (int i = 0; i < 16; i++) vbuf[i] = tile[tchunk + i][ocol];
  u16* dst = vt + (size_t)(cb * 64 + ocol) * T_SEQ + tb * 64 + tchunk;
  *(u32x4*)dst = *(u32x4*)&vbuf[0];
  *(u32x4*)(dst + 8) = *(u32x4*)&vbuf[8];
}

// ---------------- causal flash attention ----------------
// q,k split hi/lo from f32 qkv (fp32-accurate scores); probs/V bf16; out hi bf16
__global__ __launch_bounds__(256) void attn_kernel(
    const float* __restrict__ qkv, const u16* __restrict__ vt,
    u16* __restrict__ outh) {
  constexpr float SCALE = 0.08838834764831845f;
  __shared__ u16 Kh[32][136], Kl[32][136];
  __shared__ u16 Vt_lds[128][40];
  __shared__ u16 P_lds[4][16][40];
  int tid = threadIdx.x;
  int wid = tid >> 6, lane = tid & 63;
  int g16 = lane >> 4, l16 = lane & 15;
  int h = blockIdx.x & 31;
  int qt = blockIdx.x >> 5;
  int qb = qt * 64;

  bf16x8 qh[4], ql[4];
  {
    const float* qsrc = qkv + (size_t)(qb + wid * 16 + l16) * QKV_N + h * 128;
#pragma unroll
    for (int ds = 0; ds < 4; ds++) {
      float v[8];
      *(float4*)&v[0] = *(const float4*)(qsrc + ds * 32 + g16 * 8);
      *(float4*)&v[4] = *(const float4*)(qsrc + ds * 32 + g16 * 8 + 4);
      u32x4 H, L;
      split8(v, H, L);
      qh[ds] = __builtin_bit_cast(bf16x8, H);
      ql[ds] = __builtin_bit_cast(bf16x8, L);
    }
  }
  f32x4 oacc[8] = {};
  float mrun[4] = {-1e30f, -1e30f, -1e30f, -1e30f};
  float lrun[4] = {0.f, 0.f, 0.f, 0.f};

  int st_k = tid >> 3, st_d = (tid & 7) * 16;
  int sv_d = tid >> 1, sv_k = (tid & 1) * 16;

  int ktiles = (qb + 64) >> 5;
  for (int kt = 0; kt < ktiles; kt++) {
    __syncthreads();
    {
      const float* src = qkv + (size_t)(kt * 32 + st_k) * QKV_N + HID + h * 128 + st_d;
      float v[16];
      *(float4*)&v[0] = *(const float4*)(src);
      *(float4*)&v[4] = *(const float4*)(src + 4);
      *(float4*)&v[8] = *(const float4*)(src + 8);
      *(float4*)&v[12] = *(const float4*)(src + 12);
      u32x4 H, L;
      split8(&v[0], H, L);
      *(u32x4*)&Kh[st_k][st_d] = H;
      *(u32x4*)&Kl[st_k][st_d] = L;
      split8(&v[8], H, L);
      *(u32x4*)&Kh[st_k][st_d + 8] = H;
      *(u32x4*)&Kl[st_k][st_d + 8] = L;
    }
    {
      const u16* src = vt + (size_t)(h * 128 + sv_d) * T_SEQ + kt * 32 + sv_k;
      *(u32x4*)&Vt_lds[sv_d][sv_k] = *(const u32x4*)src;
      *(u32x4*)&Vt_lds[sv_d][sv_k + 8] = *(const u32x4*)(src + 8);
    }
    __syncthreads();
    f32x4 sacc[2] = {};
#pragma unroll
    for (int kb = 0; kb < 2; kb++)
#pragma unroll
      for (int ds = 0; ds < 4; ds++) {
        bf16x8 kfh = __builtin_bit_cast(bf16x8,
            *(const u32x4*)&Kh[kb * 16 + l16][ds * 32 + g16 * 8]);
        bf16x8 kfl = __builtin_bit_cast(bf16x8,
            *(const u32x4*)&Kl[kb * 16 + l16][ds * 32 + g16 * 8]);
        sacc[kb] = __builtin_amdgcn_mfma_f32_16x16x32_bf16(qh[ds], kfh, sacc[kb], 0, 0, 0);
        sacc[kb] = __builtin_amdgcn_mfma_f32_16x16x32_bf16(ql[ds], kfh, sacc[kb], 0, 0, 0);
        sacc[kb] = __builtin_amdgcn_mfma_f32_16x16x32_bf16(qh[ds], kfl, sacc[kb], 0, 0, 0);
      }
    float p0v[4], p1v[4];
#pragma unroll
    for (int r = 0; r < 4; r++) {
      int qrow = qb + wid * 16 + g16 * 4 + r;
      bool msk0 = (kt * 32 + l16) > qrow;
      bool msk1 = (kt * 32 + 16 + l16) > qrow;
      float s0 = msk0 ? -1e30f : sacc[0][r] * SCALE;
      float s1 = msk1 ? -1e30f : sacc[1][r] * SCALE;
      float tm = fmaxf(s0, s1);
      tm = fmaxf(tm, __shfl_xor(tm, 1));
      tm = fmaxf(tm, __shfl_xor(tm, 2));
      tm = fmaxf(tm, __shfl_xor(tm, 4));
      tm = fmaxf(tm, __shfl_xor(tm, 8));
      float mnew = fmaxf(mrun[r], tm);
      float fac = __expf(mrun[r] - mnew);
      float p0 = msk0 ? 0.f : __expf(s0 - mnew);
      float p1 = msk1 ? 0.f : __expf(s1 - mnew);
      float ts = p0 + p1;
      ts += __shfl_xor(ts, 1);
      ts += __shfl_xor(ts, 2);
      ts += __shfl_xor(ts, 4);
      ts += __shfl_xor(ts, 8);
      lrun[r] = lrun[r] * fac + ts;
      mrun[r] = mnew;
      p0v[r] = p0; p1v[r] = p1;
#pragma unroll
      for (int db = 0; db < 8; db++) oacc[db][r] *= fac;
    }
#pragma unroll
    for (int r = 0; r < 4; r++) {
      P_lds[wid][g16 * 4 + r][l16] = f2bf(p0v[r]);
      P_lds[wid][g16 * 4 + r][16 + l16] = f2bf(p1v[r]);
    }
    __syncthreads();
    bf16x8 pa = __builtin_bit_cast(bf16x8, *(const u32x4*)&P_lds[wid][l16][g16 * 8]);
#pragma unroll
    for (int db = 0; db < 8; db++) {
      bf16x8 vb = __builtin_bit_cast(bf16x8,
          *(const u32x4*)&Vt_lds[db * 16 + l16][g16 * 8]);
      oacc[db] = __builtin_amdgcn_mfma_f32_16x16x32_bf16(pa, vb, oacc[db], 0, 0, 0);
    }
  }
#pragma unroll
  for (int r = 0; r < 4; r++) {
    int qrow = qb + wid * 16 + g16 * 4 + r;
    float inv = 1.f / lrun[r];
#pragma unroll
    for (int db = 0; db < 8; db++)
      outh[(size_t)qrow * HID + h * 128 + db * 16 + l16] =
          f2bf(oacc[db][r] * inv);
  }
}

// ---------------- silu(gate)*up : gup bf16 -> hi bf16 plane ----------------
__global__ __launch_bounds__(256) void silu_mul_kernel(
    const u16* __restrict__ gu, u16* __restrict__ acth) {
  size_t e = ((size_t)blockIdx.x * 256 + threadIdx.x) * 8;
  size_t row = e / I_FF;
  int col = (int)(e % I_FF);
  const u16* gp = gu + row * GU_N + col;
  u32x4 gv = *(const u32x4*)gp;
  u32x4 uv = *(const u32x4*)(gp + I_FF);
  u32x4 H;
#pragma unroll
  for (int j = 0; j < 4; j++) {
    float g0 = bf2f((u16)(gv[j] & 0xffff)), g1 = bf2f((u16)(gv[j] >> 16));
    float u0 = bf2f((u16)(uv[j] & 0xffff)), u1 = bf2f((u16)(uv[j] >> 16));
    float o0 = g0 / (1.f + __expf(-g0)) * u0;
    float o1 = g1 / (1.f + __expf(-g1)) * u1;
    H[j] = (u32)f2bf(o0) | ((u32)f2bf(o1) << 16);
  }
  *(u32x4*)(acth + row * I_FF + col) = H;
}

extern "C" void kernel_launch(void* const* d_in, const int* in_sizes, int n_in,
                              void* d_out, int out_size, void* d_ws, size_t ws_size,
                              hipStream_t stream) {
  const float* hs    = (const float*)d_in[1];
  const float* ln1   = (const float*)d_in[2];
  const float* ln2   = (const float*)d_in[3];
  const int* qkv_qw  = (const int*)d_in[4];
  const float* qkv_s = (const float*)d_in[5];
  const int* qkv_z   = (const int*)d_in[6];
  const int* o_qw    = (const int*)d_in[7];
  const float* o_s   = (const float*)d_in[8];
  const int* o_z     = (const int*)d_in[9];
  const int* gu_qw   = (const int*)d_in[10];
  const float* gu_s  = (const float*)d_in[11];
  const int* gu_z    = (const int*)d_in[12];
  const int* dn_qw   = (const int*)d_in[13];
  const float* dn_s  = (const float*)d_in[14];
  const int* dn_z    = (const int*)d_in[15];

  char* ws = (char*)d_ws;
  u16*   xnh    = (u16*)(ws);                        // 16MB
  float* qkv    = (float*)(ws + (size_t)33554432);   // 96MB region
  u16*   vt     = (u16*)(ws + (size_t)134217728);    // 16MB
  float* hidden = (float*)(ws + (size_t)150994944);  // 32MB
  u16*   gup    = (u16*)(ws + (size_t)184549376);    // 88MB region
  u16*   attnh  = xnh;                    // xn dead after qkv GEMM
  u16*   acth   = (u16*)qkv;              // qkv region start, gu pack is +48MB
  // packed weight scratch (regions dead at time of use):
  u32* pk_gup = (u32*)gup;    // qkv(25.2MB) / o(8.4MB) / down(22.5MB) packs
  u32* pk_qkv = (u32*)((char*)qkv + (size_t)50331648);  // gu pack (45.1MB)

  // grid = 8 xcd * 2 mig * (N/256)
  auto grid256 = [](int N) { return 16 * (N / 256); };

  rmsnorm_kernel<<<T_SEQ, 256, 0, stream>>>(hs, ln1, xnh);
  pack_qw_kernel<<<dim3(QKV_N / 256, HID / 8), 256, 0, stream>>>(qkv_qw, pk_gup, QKV_N);
  awq_gemm256r_kernel<false, false><<<grid256(QKV_N), 512, 0, stream>>>(
      xnh, pk_gup, qkv_s, qkv_z, nullptr, qkv, QKV_N, HID, QKV_N / 256);
  rope_kernel<<<T_SEQ, 256, 0, stream>>>(qkv);
  transpose_v_kernel<<<dim3(T_SEQ / 64, HID / 64), 256, 0, stream>>>(qkv, vt);
  attn_kernel<<<NHEADS * (T_SEQ / 64), 256, 0, stream>>>(qkv, vt, attnh);
  pack_qw_kernel<<<dim3(HID / 256, HID / 8), 256, 0, stream>>>(o_qw, pk_gup, HID);
  awq_gemm256r_kernel<true, false><<<grid256(HID), 512, 0, stream>>>(
      attnh, pk_gup, o_s, o_z, hs, hidden, HID, HID, HID / 256);
  rmsnorm_kernel<<<T_SEQ, 256, 0, stream>>>(hidden, ln2, xnh);
  pack_qw_kernel<<<dim3(GU_N / 256, HID / 8), 256, 0, stream>>>(gu_qw, pk_qkv, GU_N);
  awq_gemm256r_kernel<false, true><<<grid256(GU_N), 512, 0, stream>>>(
      xnh, pk_qkv, gu_s, gu_z, nullptr, gup, GU_N, HID, GU_N / 256);
  silu_mul_kernel<<<(T_SEQ * (size_t)I_FF / 8 / 256), 256, 0, stream>>>(gup, acth);
  pack_qw_kernel<<<dim3(HID / 256, I_FF / 8), 256, 0, stream>>>(dn_qw, pk_gup, HID);
  awq_gemm256r_kernel<true, false><<<grid256(HID), 512, 0, stream>>>(
      acth, pk_gup, dn_s, dn_z, hidden, (float*)d_out, HID, I_FF, HID / 256);
}

// Round 18
// 1583.048 us; speedup vs baseline: 1.2003x; 1.2003x over previous
//
#include <hip/hip_runtime.h>
#include <stdint.h>

#define T_SEQ 2048
#define HID 4096
#define NHEADS 32
#define I_FF 11008
#define QKV_N 12288
#define GU_N 22016

typedef unsigned short u16;
typedef unsigned int u32;
typedef __attribute__((ext_vector_type(4))) float f32x4;
typedef __attribute__((ext_vector_type(8))) __bf16 bf16x8;
typedef __attribute__((ext_vector_type(4))) u32 u32x4;
typedef __attribute__((ext_vector_type(2))) u32 u32x2;

__device__ __forceinline__ u16 f2bf(float f) {
  union { float f; u32 u; } v; v.f = f;
  u32 u = v.u;
  return (u16)((u + 0x7fffu + ((u >> 16) & 1u)) >> 16);
}
__device__ __forceinline__ float bf2f(u16 h) {
  union { u32 u; float f; } v; v.u = ((u32)h) << 16;
  return v.f;
}
__device__ __forceinline__ void split2(float x, u16& hi, u16& lo) {
  hi = f2bf(x);
  lo = f2bf(x - bf2f(hi));
}
// 8 floats -> hi-pack and lo-pack (each 8 bf16 in a u32x4)
__device__ __forceinline__ void split8(const float* v, u32x4& H, u32x4& L) {
#pragma unroll
  for (int j = 0; j < 4; j++) {
    u16 h0, l0, h1, l1;
    split2(v[2 * j], h0, l0);
    split2(v[2 * j + 1], h1, l1);
    H[j] = (u32)h0 | ((u32)h1 << 16);
    L[j] = (u32)l0 | ((u32)l1 << 16);
  }
}
// dequant 8 packed nibbles - zq -> 8 bf16 (exact: |q-z|<=15 has <=4 mantissa
// bits -> top-16-bit truncation is exact). perm packs the two high halves.
__device__ __forceinline__ void dq8(u32 rbp, int zq, u32x4& w) {
#pragma unroll
  for (int j = 0; j < 4; j++) {
    int q0 = (int)((rbp >> (8 * j)) & 15u) - zq;
    int q1 = (int)((rbp >> (8 * j + 4)) & 15u) - zq;
    u32 b0 = __builtin_bit_cast(u32, (float)q0);
    u32 b1 = __builtin_bit_cast(u32, (float)q1);
    w[j] = __builtin_amdgcn_perm(b1, b0, 0x07060302u);
  }
}

// ---------------- weight repack: int32 (0..15) -> packed nibbles ----------------
// pw[oct][n] u32, nibble j = qw[oct*8+j][n]
__global__ __launch_bounds__(256) void pack_qw_kernel(
    const int* __restrict__ qw, u32* __restrict__ pw, int N) {
  int n = blockIdx.x * 256 + threadIdx.x;
  int oct = blockIdx.y;
  const int* src = qw + (size_t)oct * 8 * N + n;
  u32 v = 0;
#pragma unroll
  for (int j = 0; j < 8; j++)
    v |= ((u32)src[(size_t)j * N] & 15u) << (4 * j);
  pw[(size_t)oct * N + n] = v;
}

// ---------------- RMSNorm: f32 in -> hi bf16 plane ----------------
__global__ __launch_bounds__(256) void rmsnorm_kernel(
    const float* __restrict__ in, const float* __restrict__ w,
    u16* __restrict__ outh) {
  int row = blockIdx.x;
  const float* x = in + (size_t)row * HID;
  float4 vals[4];
  float ss = 0.f;
#pragma unroll
  for (int k = 0; k < 4; k++) {
    vals[k] = ((const float4*)x)[threadIdx.x + k * 256];
    ss += vals[k].x * vals[k].x + vals[k].y * vals[k].y +
          vals[k].z * vals[k].z + vals[k].w * vals[k].w;
  }
#pragma unroll
  for (int o = 1; o < 64; o <<= 1) ss += __shfl_xor(ss, o);
  __shared__ float red[4];
  if ((threadIdx.x & 63) == 0) red[threadIdx.x >> 6] = ss;
  __syncthreads();
  ss = red[0] + red[1] + red[2] + red[3];
  float rs = rsqrtf(ss * (1.f / HID) + 1e-6f);
#pragma unroll
  for (int k = 0; k < 4; k++) {
    int c4 = threadIdx.x + k * 256;
    float4 wv = ((const float4*)w)[c4];
    float o[4] = {vals[k].x * rs * wv.x, vals[k].y * rs * wv.y,
                  vals[k].z * rs * wv.z, vals[k].w * rs * wv.w};
    u32x2 H;
    H[0] = (u32)f2bf(o[0]) | ((u32)f2bf(o[1]) << 16);
    H[1] = (u32)f2bf(o[2]) | ((u32)f2bf(o[3]) << 16);
    *(u32x2*)(outh + (size_t)row * HID + c4 * 4) = H;
  }
}

// ---------------- AWQ GEMM, BN=256, A-hi, packed-nibble B (all 4 GEMMs) ----------------
// BM=128 BN=256 BK=32, 8 waves (2M x 4N), per-wave 64x64 out (4m x 4n frags).
// In-loop exact dequant (q-z)->bf16 (block-shared via LDS); telescoping scale.
// m-partitioned XCD decode: each XCD owns 2 m-tiles -> A L2-resident all dispatch.
template <bool RESID, bool OUTBF16>
__global__ __launch_bounds__(512) void awq_gemm256_kernel(
    const u16* __restrict__ Ahg,
    const u32* __restrict__ pw, const float* __restrict__ scales,
    const int* __restrict__ qz, const float* __restrict__ resid,
    void* __restrict__ outp, int N, int K, int nstrips) {
  __shared__ u16 AhL[2][128][40];
  __shared__ u16 BqL[2][256][40];
  int tid = threadIdx.x;
  int lane = tid & 63;
  int wid = tid >> 6;
  int g16 = lane >> 4, l16 = lane & 15;
  int p = blockIdx.x;
  int xcd = p & 7;
  int idx = p >> 3;
  int s = idx >> 1;
  int mi = ((idx & 1) << 3) + xcd;
  if (s >= nstrips) return;
  int m0 = mi * 128;
  int n0 = s * 256;
  int wr = wid >> 2, wc = wid & 3;   // 2 row halves x 4 col quarters

  f32x4 acc[4][4] = {};
  float svold[4];

  // A staging: thread -> (row, 8-wide k-chunk)
  int a_row = tid >> 2, a_kc = (tid & 3) * 8;
  const u16* aph = Ahg + (size_t)(m0 + a_row) * K + a_kc;
  // B staging: thread -> (col, 2 consecutive octs) = 2 packed u32 per step
  int b_n = tid & 255;
  int b_oct = (tid >> 8) * 2;        // 0 or 2
  int b_kb = b_oct * 8;              // 0 or 16
  const u32* pwp = pw + (size_t)b_oct * N + n0 + b_n;
  const float* scp = scales + n0;
  const int* qzp = qz + n0 + b_n;

  int nsteps = K >> 5;

  u32x4 rah;
  u32 rb0, rb1;

  auto load_step = [&](int ks) {
    int k0 = ks << 5;
    rah = *(const u32x4*)(aph + k0);
    const u32* q = pwp + (size_t)(ks << 2) * N;
    rb0 = q[0];
    rb1 = q[N];
  };
  auto write_step = [&](int buf, int zq) {
    *(u32x4*)&AhL[buf][a_row][a_kc] = rah;
    u32x4 w0, w1;
    dq8(rb0, zq, w0);
    dq8(rb1, zq, w1);
    *(u32x4*)&BqL[buf][b_n][b_kb] = w0;
    *(u32x4*)&BqL[buf][b_n][b_kb + 8] = w1;
  };

  int zq = qzp[0];
  load_step(0);
  write_step(0, zq);
#pragma unroll
  for (int n = 0; n < 4; n++)
    svold[n] = scp[wc * 64 + n * 16 + l16];
  __syncthreads();

  int cur = 0;
  for (int ks = 0; ks < nsteps; ks++) {
    int nxt = ks + 1;
    if (nxt < nsteps) {
      if ((nxt & 3) == 0) zq = qzp[(size_t)(nxt >> 2) * N];
      load_step(nxt);                    // issue-early (hides under MFMA)
    }
    // entering a new scale group: rescale acc into new units
    if (ks != 0 && (ks & 3) == 0) {
      int g = ks >> 2;
#pragma unroll
      for (int n = 0; n < 4; n++) {
        float svnew = scp[(size_t)g * N + wc * 64 + n * 16 + l16];
        float r = svold[n] * __builtin_amdgcn_rcpf(svnew);
        svold[n] = svnew;
#pragma unroll
        for (int m = 0; m < 4; m++)
#pragma unroll
          for (int i = 0; i < 4; i++) acc[m][n][i] *= r;
      }
    }
    // compute on buf cur
    bf16x8 bq[4];
#pragma unroll
    for (int n = 0; n < 4; n++)
      bq[n] = __builtin_bit_cast(bf16x8,
          *(const u32x4*)&BqL[cur][wc * 64 + n * 16 + l16][g16 * 8]);
    __builtin_amdgcn_s_setprio(1);
#pragma unroll
    for (int m = 0; m < 4; m++) {
      bf16x8 ah = __builtin_bit_cast(bf16x8,
          *(const u32x4*)&AhL[cur][wr * 64 + m * 16 + l16][g16 * 8]);
#pragma unroll
      for (int n = 0; n < 4; n++)
        acc[m][n] = __builtin_amdgcn_mfma_f32_16x16x32_bf16(ah, bq[n], acc[m][n], 0, 0, 0);
    }
    __builtin_amdgcn_s_setprio(0);
    if (nxt < nsteps) write_step(cur ^ 1, zq);   // write-late (other buffer)
    __syncthreads();
    cur ^= 1;
  }
  // fold final group scale
#pragma unroll
  for (int n = 0; n < 4; n++)
#pragma unroll
    for (int m = 0; m < 4; m++)
#pragma unroll
      for (int i = 0; i < 4; i++) acc[m][n][i] *= svold[n];
  // epilogue: C layout col=lane&15, row=(lane>>4)*4+reg
#pragma unroll
  for (int m = 0; m < 4; m++) {
#pragma unroll
    for (int n = 0; n < 4; n++) {
#pragma unroll
      for (int r = 0; r < 4; r++) {
        int row = m0 + wr * 64 + m * 16 + g16 * 4 + r;
        int col = n0 + wc * 64 + n * 16 + l16;
        float v = acc[m][n][r];
        if (RESID) v += resid[(size_t)row * N + col];
        if (OUTBF16)
          ((u16*)outp)[(size_t)row * N + col] = f2bf(v);
        else
          ((float*)outp)[(size_t)row * N + col] = v;
      }
    }
  }
}

// ---------------- RoPE in-place on q,k of qkv (f32) ----------------
__global__ __launch_bounds__(256) void rope_kernel(float* __restrict__ qkv) {
  int t = blockIdx.x;
  __shared__ float cs[64], sn[64];
  if (threadIdx.x < 64) {
    int i = threadIdx.x;
    float freq = exp2f(-(float)i * (13.287712379549449f / 64.f));
    float ang = (float)t * freq;
    cs[i] = cosf(ang);
    sn[i] = sinf(ang);
  }
  __syncthreads();
#pragma unroll
  for (int it = 0; it < 16; it++) {
    int idx = threadIdx.x + it * 256;
    int part = idx >> 11;
    int rem = idx & 2047;
    int hh = rem >> 6, i = rem & 63;
    float* base = qkv + (size_t)t * QKV_N + (size_t)part * HID + hh * 128;
    float x1 = base[i], x2 = base[64 + i];
    float c = cs[i], s = sn[i];
    base[i] = x1 * c - x2 * s;
    base[64 + i] = x2 * c + x1 * s;
  }
}

// ---------------- transpose V section of qkv(f32) -> vt[H][T] bf16 ----------------
__global__ __launch_bounds__(256) void transpose_v_kernel(
    const float* __restrict__ qkv, u16* __restrict__ vt) {
  __shared__ u16 tile[64][65];
  int tb = blockIdx.x;
  int cb = blockIdx.y;
  int tid = threadIdx.x;
  int r = tid >> 2, c16 = (tid & 3) * 16;
  const float* src = qkv + (size_t)(tb * 64 + r) * QKV_N + 2 * HID + cb * 64 + c16;
  float v[16];
  *(float4*)&v[0] = *(const float4*)(src);
  *(float4*)&v[4] = *(const float4*)(src + 4);
  *(float4*)&v[8] = *(const float4*)(src + 8);
  *(float4*)&v[12] = *(const float4*)(src + 12);
#pragma unroll
  for (int i = 0; i < 16; i++) tile[r][c16 + i] = f2bf(v[i]);
  __syncthreads();
  int ocol = tid >> 2, tchunk = (tid & 3) * 16;
  u16 vbuf[16];
#pragma unroll
  for (int i = 0; i < 16; i++) vbuf[i] = tile[tchunk + i][ocol];
  u16* dst = vt + (size_t)(cb * 64 + ocol) * T_SEQ + tb * 64 + tchunk;
  *(u32x4*)dst = *(u32x4*)&vbuf[0];
  *(u32x4*)(dst + 8) = *(u32x4*)&vbuf[8];
}

// ---------------- causal flash attention ----------------
// q,k split hi/lo from f32 qkv (fp32-accurate scores); probs/V bf16; out hi bf16
__global__ __launch_bounds__(256) void attn_kernel(
    const float* __restrict__ qkv, const u16* __restrict__ vt,
    u16* __restrict__ outh) {
  constexpr float SCALE = 0.08838834764831845f;
  __shared__ u16 Kh[32][136], Kl[32][136];
  __shared__ u16 Vt_lds[128][40];
  __shared__ u16 P_lds[4][16][40];
  int tid = threadIdx.x;
  int wid = tid >> 6, lane = tid & 63;
  int g16 = lane >> 4, l16 = lane & 15;
  int h = blockIdx.x & 31;
  int qt = blockIdx.x >> 5;
  int qb = qt * 64;

  bf16x8 qh[4], ql[4];
  {
    const float* qsrc = qkv + (size_t)(qb + wid * 16 + l16) * QKV_N + h * 128;
#pragma unroll
    for (int ds = 0; ds < 4; ds++) {
      float v[8];
      *(float4*)&v[0] = *(const float4*)(qsrc + ds * 32 + g16 * 8);
      *(float4*)&v[4] = *(const float4*)(qsrc + ds * 32 + g16 * 8 + 4);
      u32x4 H, L;
      split8(v, H, L);
      qh[ds] = __builtin_bit_cast(bf16x8, H);
      ql[ds] = __builtin_bit_cast(bf16x8, L);
    }
  }
  f32x4 oacc[8] = {};
  float mrun[4] = {-1e30f, -1e30f, -1e30f, -1e30f};
  float lrun[4] = {0.f, 0.f, 0.f, 0.f};

  int st_k = tid >> 3, st_d = (tid & 7) * 16;
  int sv_d = tid >> 1, sv_k = (tid & 1) * 16;

  int ktiles = (qb + 64) >> 5;
  for (int kt = 0; kt < ktiles; kt++) {
    __syncthreads();
    {
      const float* src = qkv + (size_t)(kt * 32 + st_k) * QKV_N + HID + h * 128 + st_d;
      float v[16];
      *(float4*)&v[0] = *(const float4*)(src);
      *(float4*)&v[4] = *(const float4*)(src + 4);
      *(float4*)&v[8] = *(const float4*)(src + 8);
      *(float4*)&v[12] = *(const float4*)(src + 12);
      u32x4 H, L;
      split8(&v[0], H, L);
      *(u32x4*)&Kh[st_k][st_d] = H;
      *(u32x4*)&Kl[st_k][st_d] = L;
      split8(&v[8], H, L);
      *(u32x4*)&Kh[st_k][st_d + 8] = H;
      *(u32x4*)&Kl[st_k][st_d + 8] = L;
    }
    {
      const u16* src = vt + (size_t)(h * 128 + sv_d) * T_SEQ + kt * 32 + sv_k;
      *(u32x4*)&Vt_lds[sv_d][sv_k] = *(const u32x4*)src;
      *(u32x4*)&Vt_lds[sv_d][sv_k + 8] = *(const u32x4*)(src + 8);
    }
    __syncthreads();
    f32x4 sacc[2] = {};
#pragma unroll
    for (int kb = 0; kb < 2; kb++)
#pragma unroll
      for (int ds = 0; ds < 4; ds++) {
        bf16x8 kfh = __builtin_bit_cast(bf16x8,
            *(const u32x4*)&Kh[kb * 16 + l16][ds * 32 + g16 * 8]);
        bf16x8 kfl = __builtin_bit_cast(bf16x8,
            *(const u32x4*)&Kl[kb * 16 + l16][ds * 32 + g16 * 8]);
        sacc[kb] = __builtin_amdgcn_mfma_f32_16x16x32_bf16(qh[ds], kfh, sacc[kb], 0, 0, 0);
        sacc[kb] = __builtin_amdgcn_mfma_f32_16x16x32_bf16(ql[ds], kfh, sacc[kb], 0, 0, 0);
        sacc[kb] = __builtin_amdgcn_mfma_f32_16x16x32_bf16(qh[ds], kfl, sacc[kb], 0, 0, 0);
      }
    float p0v[4], p1v[4];
#pragma unroll
    for (int r = 0; r < 4; r++) {
      int qrow = qb + wid * 16 + g16 * 4 + r;
      bool msk0 = (kt * 32 + l16) > qrow;
      bool msk1 = (kt * 32 + 16 + l16) > qrow;
      float s0 = msk0 ? -1e30f : sacc[0][r] * SCALE;
      float s1 = msk1 ? -1e30f : sacc[1][r] * SCALE;
      float tm = fmaxf(s0, s1);
      tm = fmaxf(tm, __shfl_xor(tm, 1));
      tm = fmaxf(tm, __shfl_xor(tm, 2));
      tm = fmaxf(tm, __shfl_xor(tm, 4));
      tm = fmaxf(tm, __shfl_xor(tm, 8));
      float mnew = fmaxf(mrun[r], tm);
      float fac = __expf(mrun[r] - mnew);
      float p0 = msk0 ? 0.f : __expf(s0 - mnew);
      float p1 = msk1 ? 0.f : __expf(s1 - mnew);
      float ts = p0 + p1;
      ts += __shfl_xor(ts, 1);
      ts += __shfl_xor(ts, 2);
      ts += __shfl_xor(ts, 4);
      ts += __shfl_xor(ts, 8);
      lrun[r] = lrun[r] * fac + ts;
      mrun[r] = mnew;
      p0v[r] = p0; p1v[r] = p1;
#pragma unroll
      for (int db = 0; db < 8; db++) oacc[db][r] *= fac;
    }
#pragma unroll
    for (int r = 0; r < 4; r++) {
      P_lds[wid][g16 * 4 + r][l16] = f2bf(p0v[r]);
      P_lds[wid][g16 * 4 + r][16 + l16] = f2bf(p1v[r]);
    }
    __syncthreads();
    bf16x8 pa = __builtin_bit_cast(bf16x8, *(const u32x4*)&P_lds[wid][l16][g16 * 8]);
#pragma unroll
    for (int db = 0; db < 8; db++) {
      bf16x8 vb = __builtin_bit_cast(bf16x8,
          *(const u32x4*)&Vt_lds[db * 16 + l16][g16 * 8]);
      oacc[db] = __builtin_amdgcn_mfma_f32_16x16x32_bf16(pa, vb, oacc[db], 0, 0, 0);
    }
  }
#pragma unroll
  for (int r = 0; r < 4; r++) {
    int qrow = qb + wid * 16 + g16 * 4 + r;
    float inv = 1.f / lrun[r];
#pragma unroll
    for (int db = 0; db < 8; db++)
      outh[(size_t)qrow * HID + h * 128 + db * 16 + l16] =
          f2bf(oacc[db][r] * inv);
  }
}

// ---------------- silu(gate)*up : gup bf16 -> hi bf16 plane ----------------
__global__ __launch_bounds__(256) void silu_mul_kernel(
    const u16* __restrict__ gu, u16* __restrict__ acth) {
  size_t e = ((size_t)blockIdx.x * 256 + threadIdx.x) * 8;
  size_t row = e / I_FF;
  int col = (int)(e % I_FF);
  const u16* gp = gu + row * GU_N + col;
  u32x4 gv = *(const u32x4*)gp;
  u32x4 uv = *(const u32x4*)(gp + I_FF);
  u32x4 H;
#pragma unroll
  for (int j = 0; j < 4; j++) {
    float g0 = bf2f((u16)(gv[j] & 0xffff)), g1 = bf2f((u16)(gv[j] >> 16));
    float u0 = bf2f((u16)(uv[j] & 0xffff)), u1 = bf2f((u16)(uv[j] >> 16));
    float o0 = g0 / (1.f + __expf(-g0)) * u0;
    float o1 = g1 / (1.f + __expf(-g1)) * u1;
    H[j] = (u32)f2bf(o0) | ((u32)f2bf(o1) << 16);
  }
  *(u32x4*)(acth + row * I_FF + col) = H;
}

extern "C" void kernel_launch(void* const* d_in, const int* in_sizes, int n_in,
                              void* d_out, int out_size, void* d_ws, size_t ws_size,
                              hipStream_t stream) {
  const float* hs    = (const float*)d_in[1];
  const float* ln1   = (const float*)d_in[2];
  const float* ln2   = (const float*)d_in[3];
  const int* qkv_qw  = (const int*)d_in[4];
  const float* qkv_s = (const float*)d_in[5];
  const int* qkv_z   = (const int*)d_in[6];
  const int* o_qw    = (const int*)d_in[7];
  const float* o_s   = (const float*)d_in[8];
  const int* o_z     = (const int*)d_in[9];
  const int* gu_qw   = (const int*)d_in[10];
  const float* gu_s  = (const float*)d_in[11];
  const int* gu_z    = (const int*)d_in[12];
  const int* dn_qw   = (const int*)d_in[13];
  const float* dn_s  = (const float*)d_in[14];
  const int* dn_z    = (const int*)d_in[15];

  char* ws = (char*)d_ws;
  u16*   xnh    = (u16*)(ws);                        // 16MB
  float* qkv    = (float*)(ws + (size_t)33554432);   // 96MB region
  u16*   vt     = (u16*)(ws + (size_t)134217728);    // 16MB
  float* hidden = (float*)(ws + (size_t)150994944);  // 32MB
  u16*   gup    = (u16*)(ws + (size_t)184549376);    // 88MB region
  u16*   attnh  = xnh;                    // xn dead after qkv GEMM
  u16*   acth   = (u16*)qkv;              // qkv region start, gu pack is +48MB
  // packed weight scratch (regions dead at time of use):
  u32* pk_gup = (u32*)gup;    // qkv(25.2MB) / o(8.4MB) / down(22.5MB) packs
  u32* pk_qkv = (u32*)((char*)qkv + (size_t)50331648);  // gu pack (45.1MB)

  // grid = 8 xcd * 2 mig * (N/256)
  auto grid256 = [](int N) { return 16 * (N / 256); };

  rmsnorm_kernel<<<T_SEQ, 256, 0, stream>>>(hs, ln1, xnh);
  pack_qw_kernel<<<dim3(QKV_N / 256, HID / 8), 256, 0, stream>>>(qkv_qw, pk_gup, QKV_N);
  awq_gemm256_kernel<false, false><<<grid256(QKV_N), 512, 0, stream>>>(
      xnh, pk_gup, qkv_s, qkv_z, nullptr, qkv, QKV_N, HID, QKV_N / 256);
  rope_kernel<<<T_SEQ, 256, 0, stream>>>(qkv);
  transpose_v_kernel<<<dim3(T_SEQ / 64, HID / 64), 256, 0, stream>>>(qkv, vt);
  attn_kernel<<<NHEADS * (T_SEQ / 64), 256, 0, stream>>>(qkv, vt, attnh);
  pack_qw_kernel<<<dim3(HID / 256, HID / 8), 256, 0, stream>>>(o_qw, pk_gup, HID);
  awq_gemm256_kernel<true, false><<<grid256(HID), 512, 0, stream>>>(
      attnh, pk_gup, o_s, o_z, hs, hidden, HID, HID, HID / 256);
  rmsnorm_kernel<<<T_SEQ, 256, 0, stream>>>(hidden, ln2, xnh);
  pack_qw_kernel<<<dim3(GU_N / 256, HID / 8), 256, 0, stream>>>(gu_qw, pk_qkv, GU_N);
  awq_gemm256_kernel<false, true><<<grid256(GU_N), 512, 0, stream>>>(
      xnh, pk_qkv, gu_s, gu_z, nullptr, gup, GU_N, HID, GU_N / 256);
  silu_mul_kernel<<<(T_SEQ * (size_t)I_FF / 8 / 256), 256, 0, stream>>>(gup, acth);
  pack_qw_kernel<<<dim3(HID / 256, I_FF / 8), 256, 0, stream>>>(dn_qw, pk_gup, HID);
  awq_gemm256_kernel<true, false><<<grid256(HID), 512, 0, stream>>>(
      acth, pk_gup, dn_s, dn_z, hidden, (float*)d_out, HID, I_FF, HID / 256);
}